// Round 5
// baseline (1194.706 us; speedup 1.0000x reference)
//
#include <hip/hip_runtime.h>
#include <math.h>

// Problem constants (fixed by setup_inputs)
constexpr int C_  = 1024;
constexpr int H_  = 128;
constexpr int W_  = 128;
constexpr int HW_ = H_ * W_;
constexpr int N_  = 8192;
constexpr int NCOMP = 28;      // cost, g[6], H upper-tri[21]
constexpr int ITERS = 10;
constexpr int NB_ = 2048;      // blocks for wave-per-point kernels (4 pts/block)
constexpr int ROWF = 3 * C_;   // interleaved qgg row: q | gx | gy

// state layout (floats):
//  0-8   R (row-major)   9-11 t   12 lam   13 prev
//  14-22 R_new   23-25 t_new   26-31 delta
//  32-40 K1   41 fx   42 fy   43 size_ratio   72 nan flag for delta

// ----------------------------------------------- setup: init pose + pts0/pix0
__global__ void k_setup(const float* __restrict__ q, const float* __restrict__ r,
                        const float* __restrict__ K1, const int* __restrict__ srp,
                        const float* __restrict__ p3d, const float* __restrict__ p2d,
                        float* __restrict__ st, float* __restrict__ pts0,
                        int* __restrict__ pix0, int* __restrict__ cnt) {
    int n = blockIdx.x * blockDim.x + threadIdx.x;
    if (n < N_) {
        float sr = (float)srp[0];
        float ph[4] = { p3d[n*3+0], p3d[n*3+1], p3d[n*3+2], 1.f };
        float h[4];
        for (int i = 0; i < 4; i++) {
            float s = 0.f;
            for (int j = 0; j < 4; j++) s += r[i*4+j] * ph[j];
            h[i] = s;
        }
        pts0[n*3+0] = h[0]/h[3];
        pts0[n*3+1] = h[1]/h[3];
        pts0[n*3+2] = h[2]/h[3];
        int ix = (int)floorf(p2d[n*2+0] / sr); ix = min(max(ix, 0), W_-1);
        int iy = (int)floorf(p2d[n*2+1] / sr); iy = min(max(iy, 0), H_-1);
        pix0[n] = iy * W_ + ix;
    }
    if (blockIdx.x == 0 && threadIdx.x < 32) cnt[threadIdx.x] = 0;  // iter counters
    if (blockIdx.x == 0 && threadIdx.x == 0) {
        // invert r_matrix (4x4) via Gauss-Jordan in double
        double a[4][8];
        for (int i = 0; i < 4; i++)
            for (int j = 0; j < 4; j++) { a[i][j] = r[i*4+j]; a[i][j+4] = (i == j) ? 1.0 : 0.0; }
        for (int col = 0; col < 4; col++) {
            int piv = col; double mx = fabs(a[col][col]);
            for (int i = col+1; i < 4; i++) if (fabs(a[i][col]) > mx) { mx = fabs(a[i][col]); piv = i; }
            if (piv != col) for (int j = 0; j < 8; j++) { double t = a[col][j]; a[col][j] = a[piv][j]; a[piv][j] = t; }
            double d = a[col][col];
            for (int j = 0; j < 8; j++) a[col][j] /= d;
            for (int i = 0; i < 4; i++) if (i != col) {
                double f = a[i][col];
                for (int j = 0; j < 8; j++) a[i][j] -= f * a[col][j];
            }
        }
        double rel[4][4];
        for (int i = 0; i < 4; i++)
            for (int j = 0; j < 4; j++) {
                double s = 0;
                for (int k = 0; k < 4; k++) s += (double)q[i*4+k] * a[k][j+4];
                rel[i][j] = s;
            }
        for (int i = 0; i < 3; i++)
            for (int j = 0; j < 3; j++) st[i*3+j] = (float)rel[i][j];
        st[9]  = (float)rel[3][0];
        st[10] = (float)rel[3][1];
        st[11] = (float)rel[3][2];
        st[12] = 0.01f;                 // LAMBDA0
        st[13] = __builtin_inff();      // prev
        for (int i = 0; i < 9; i++) st[32+i] = K1[i];
        st[41] = K1[0]; st[42] = K1[4];
        st[43] = (float)srp[0];
        st[72] = 0.f;
    }
}

// ---------------- sobel + transpose (C,H,W) -> interleaved (HW, [q|gx|gy]*C)
// CT=32 channels so a wave's 32 lanes write 128B full cache lines.
// YT=4 rows, XT=32 cols; LDS = 32*211*4 = 27KB -> 5 blocks/CU.
__global__ void k_sobelT(const float* __restrict__ src, float* __restrict__ qgg) {
    constexpr int CT = 32, YT = 4, XT = 32;
    constexpr int RS = YT + 2;        // 6 halo rows
    constexpr int CS = XT + 2;        // 34 halo cols
    constexpr int PCS = 35;           // padded col stride
    constexpr int CHS = RS * PCS + 1; // 211 (odd) per-channel stride
    __shared__ float lds[CT * CHS];
    const int x0 = blockIdx.x * XT;
    const int y0 = blockIdx.y * YT;
    const int cc = blockIdx.z * CT;
    const int tid = threadIdx.x;
    for (int idx = tid; idx < CT * RS * CS; idx += 256) {
        int c   = idx / (RS * CS);
        int rem = idx % (RS * CS);
        int r   = rem / CS;
        int x   = rem % CS;
        int gy  = y0 + r - 1;
        int gx  = x0 + x - 1;
        float v = 0.f;
        if (gy >= 0 && gy < H_ && gx >= 0 && gx < W_)
            v = src[(size_t)(cc + c) * HW_ + gy * W_ + gx];
        lds[c * CHS + r * PCS + x] = v;
    }
    __syncthreads();
    const int c    = tid & 31;
    const int slot = tid >> 5;          // 0..7
    const int row  = slot >> 1;         // 0..3
    const int xh   = (slot & 1) * 16;   // 0 or 16
    const float* Lt = &lds[c * CHS + row * PCS + xh];
    const float* Lm = Lt + PCS;
    const float* Lb = Lm + PCS;
    size_t o = ((size_t)((y0 + row) * W_ + x0 + xh)) * ROWF + cc + c;
    float t0l = Lt[0], t0m = Lt[1];
    float t1l = Lm[0], t1m = Lm[1];
    float t2l = Lb[0], t2m = Lb[1];
    for (int cx = 0; cx < 16; cx++, o += ROWF) {
        float t0r = Lt[cx + 2];
        float t1r = Lm[cx + 2];
        float t2r = Lb[cx + 2];
        qgg[o]          = t1m;
        qgg[o + C_]     = (t0r - t0l) + 2.f*(t1r - t1l) + (t2r - t2l);
        qgg[o + 2*C_]   = (t2l + 2.f*t2m + t2r) - (t0l + 2.f*t0m + t0r);
        t0l = t0m; t0m = t0r;
        t1l = t1m; t1m = t1r;
        t2l = t2m; t2m = t2r;
    }
}

// ------------- feat0 direct channel-gather from native-layout reference map
// wave per point; lane reads 16 channels (stride HW_), writes coalesced.
__global__ __launch_bounds__(256) void k_feat0d(const float* __restrict__ rf,
                                                const int* __restrict__ pix0,
                                                float* __restrict__ feat0) {
    const int w = threadIdx.x >> 6, lane = threadIdx.x & 63;
    const int n = blockIdx.x * 4 + w;
    const int p = pix0[n];
    const float* base = rf + p;
    float* dst = feat0 + (size_t)n * C_;
#pragma unroll
    for (int i = 0; i < 16; i++) {
        int c = lane + 64 * i;
        dst[c] = base[(size_t)c * HW_];
    }
}

__device__ inline float sel6(int k, float v0, float v1, float v2,
                             float v3, float v4, float v5) {
    return k==0 ? v0 : k==1 ? v1 : k==2 ? v2 : k==3 ? v3 : k==4 ? v4 : v5;
}

// ------------------- pass A (wave-per-point) + fused reduce/solve tail block
__global__ __launch_bounds__(256, 4) void k_passA(const float* __restrict__ qgg,
        const float* __restrict__ feat0, const float* __restrict__ pts0,
        float* __restrict__ st, float* __restrict__ partial,
        int* __restrict__ cnt, int iter) {
    const int w = threadIdx.x >> 6, lane = threadIdx.x & 63;
    const int n = blockIdx.x * 4 + w;
    const float p0 = pts0[n*3+0], p1 = pts0[n*3+1], p2 = pts0[n*3+2];
    // pts1 = pts0 @ R + t (column-dot)
    const float X = p0*st[0] + p1*st[3] + p2*st[6] + st[9];
    const float Y = p0*st[1] + p1*st[4] + p2*st[7] + st[10];
    const float Z = p0*st[2] + p1*st[5] + p2*st[8] + st[11];
    const float hx = st[32]*X + st[33]*Y + st[34]*Z;
    const float hy = st[35]*X + st[36]*Y + st[37]*Z;
    const float hz = st[38]*X + st[39]*Y + st[40]*Z;
    const float sr = st[43];
    const float u = hx / hz, v = hy / hz;
    int ix = (int)floorf(u / sr); ix = min(max(ix, 0), W_-1);
    int iy = (int)floorf(v / sr); iy = min(max(iy, 0), H_-1);
    const int pix = iy * W_ + ix;

    const float4* row4 = (const float4*)(qgg + (size_t)pix * ROWF);
    const float4* f4   = (const float4*)(feat0 + (size_t)n * C_);

    float cost = 0, bx = 0, by = 0, mxx = 0, mxy = 0, myy = 0;
#pragma unroll
    for (int i = 0; i < 4; i++) {
        float4 qv = row4[      lane + 64*i];
        float4 gv = row4[256 + lane + 64*i];
        float4 yv = row4[512 + lane + 64*i];
        float4 fv = f4[lane + 64*i];
        float e;
        e = qv.x - fv.x; cost += e*e; bx += gv.x*e; by += yv.x*e; mxx += gv.x*gv.x; mxy += gv.x*yv.x; myy += yv.x*yv.x;
        e = qv.y - fv.y; cost += e*e; bx += gv.y*e; by += yv.y*e; mxx += gv.y*gv.y; mxy += gv.y*yv.y; myy += yv.y*yv.y;
        e = qv.z - fv.z; cost += e*e; bx += gv.z*e; by += yv.z*e; mxx += gv.z*gv.z; mxy += gv.z*yv.z; myy += yv.z*yv.z;
        e = qv.w - fv.w; cost += e*e; bx += gv.w*e; by += yv.w*e; mxx += gv.w*gv.w; mxy += gv.w*yv.w; myy += yv.w*yv.w;
    }
#pragma unroll
    for (int off = 32; off; off >>= 1) {
        cost += __shfl_xor(cost, off, 64);
        bx   += __shfl_xor(bx,   off, 64);
        by   += __shfl_xor(by,   off, 64);
        mxx  += __shfl_xor(mxx,  off, 64);
        mxy  += __shfl_xor(mxy,  off, 64);
        myy  += __shfl_xor(myy,  off, 64);
    }

    const float fx = st[41], fy = st[42];
    const float sc = 1.f / (Z * sr);
    const float jh00 = fx, jh02 = -fx * X / Z;
    const float jh11 = fy, jh12 = -fy * Y / Z;
    const float a00 = sc*jh00, a01 = 0.f,     a02 = sc*jh02;
    const float a03 = sc*(jh02*Y), a04 = sc*(jh00*Z - jh02*X), a05 = sc*(-jh00*Y);
    const float a10 = 0.f,     a11 = sc*jh11, a12 = sc*jh12;
    const float a13 = sc*(-jh11*Z + jh12*Y), a14 = sc*(-jh12*X), a15 = sc*(jh11*X);

    float val = 0.f;
    const int t = lane;
    if (t == 0) {
        val = cost;
    } else if (t < 7) {
        int k = t - 1;
        val = sel6(k,a00,a01,a02,a03,a04,a05)*bx + sel6(k,a10,a11,a12,a13,a14,a15)*by;
    } else if (t < NCOMP) {
        int idx = t - 7, k = 0;
        while (idx >= 6 - k) { idx -= 6 - k; k++; }
        int l = k + idx;
        float A0k = sel6(k,a00,a01,a02,a03,a04,a05);
        float A1k = sel6(k,a10,a11,a12,a13,a14,a15);
        float A0l = sel6(l,a00,a01,a02,a03,a04,a05);
        float A1l = sel6(l,a10,a11,a12,a13,a14,a15);
        val = A0k*A0l*mxx + (A0k*A1l + A1k*A0l)*mxy + A1k*A1l*myy;
    }

    __shared__ float pl[4][NCOMP];
    __shared__ int lastFlag;
    if (t < NCOMP) pl[w][t] = val;
    __syncthreads();
    if (threadIdx.x < NCOMP)
        __hip_atomic_store(&partial[(size_t)threadIdx.x * NB_ + blockIdx.x],
                           pl[0][threadIdx.x] + pl[1][threadIdx.x] +
                           pl[2][threadIdx.x] + pl[3][threadIdx.x],
                           __ATOMIC_RELAXED, __HIP_MEMORY_SCOPE_AGENT);
    __syncthreads();  // drains vmcnt: stores are at the coherent point
    if (threadIdx.x == 0) {
        int old = __hip_atomic_fetch_add(&cnt[iter], 1, __ATOMIC_RELAXED,
                                         __HIP_MEMORY_SCOPE_AGENT);
        lastFlag = (old == NB_ - 1);
    }
    __syncthreads();
    if (!lastFlag) return;

    // ---- tail: deterministic reduction (same order as previous k_RS) + solve
    __shared__ double sred[NCOMP];
    for (int j = 0; j < 7; j++) {
        int comp = w + 4 * j;
        double s = 0;
        for (int i = 0; i < NB_/64; i++)
            s += (double)__hip_atomic_load(&partial[(size_t)comp * NB_ + i*64 + lane],
                                           __ATOMIC_RELAXED, __HIP_MEMORY_SCOPE_AGENT);
        for (int off = 32; off; off >>= 1) s += __shfl_down(s, off, 64);
        if (lane == 0) sred[comp] = s;
    }
    __syncthreads();
    if (threadIdx.x != 0) return;

    if (iter == 0) st[13] = (float)(sred[0] / (double)N_);
    double g[6];
    for (int k = 0; k < 6; k++) g[k] = sred[1+k];
    double Hs[6][6];
    int idx = 7;
    for (int k = 0; k < 6; k++)
        for (int l = k; l < 6; l++) { Hs[k][l] = sred[idx]; Hs[l][k] = sred[idx]; idx++; }
    double lam = st[12];
    double M[6][7];
    for (int i = 0; i < 6; i++) {
        for (int j = 0; j < 6; j++) M[i][j] = Hs[i][j];
        M[i][i] += (Hs[i][i] + 1e-9) * lam;
        M[i][6] = -g[i];
    }
    for (int col = 0; col < 6; col++) {
        int piv = col; double mx = fabs(M[col][col]);
        for (int i = col+1; i < 6; i++) if (fabs(M[i][col]) > mx) { mx = fabs(M[i][col]); piv = i; }
        if (piv != col) for (int j = col; j < 7; j++) { double tt = M[col][j]; M[col][j] = M[piv][j]; M[piv][j] = tt; }
        double d = M[col][col];
        for (int j = col; j < 7; j++) M[col][j] /= d;
        for (int i = 0; i < 6; i++) if (i != col) {
            double f = M[i][col];
            if (f != 0.0) for (int j = col; j < 7; j++) M[i][j] -= f * M[col][j];
        }
    }
    double delta[6];
    int bad = 0;
    for (int i = 0; i < 6; i++) {
        delta[i] = M[i][6];
        st[26+i] = (float)delta[i];
        if (isnan(st[26+i])) bad = 1;
    }
    st[72] = (float)bad;
    double w0 = delta[3], w1 = delta[4], w2 = delta[5];
    double th2 = w0*w0 + w1*w1 + w2*w2 + 1e-12;
    double th = sqrt(th2);
    double Af = sin(th) / th, Bf = (1.0 - cos(th)) / th2;
    double Wm[3][3] = {{0,-w2,w1},{w2,0,-w0},{-w1,w0,0}};
    double W2[3][3];
    for (int i = 0; i < 3; i++)
        for (int j = 0; j < 3; j++) {
            double s2 = 0;
            for (int k = 0; k < 3; k++) s2 += Wm[i][k]*Wm[k][j];
            W2[i][j] = s2;
        }
    double dr[3][3];
    for (int i = 0; i < 3; i++)
        for (int j = 0; j < 3; j++)
            dr[i][j] = (i == j ? 1.0 : 0.0) + Af*Wm[i][j] + Bf*W2[i][j];
    double Rn[3][3];
    for (int i = 0; i < 3; i++)
        for (int j = 0; j < 3; j++) {
            double s2 = 0;
            for (int k = 0; k < 3; k++) s2 += dr[i][k] * (double)st[k*3+j];
            Rn[i][j] = s2;
        }
    for (int i = 0; i < 3; i++)
        for (int j = 0; j < 3; j++) st[14 + i*3 + j] = (float)Rn[i][j];
    for (int i = 0; i < 3; i++) {
        double s2 = 0;
        for (int k = 0; k < 3; k++) s2 += dr[i][k] * (double)st[9+k];
        st[23+i] = (float)(s2 + delta[i]);
    }
}

// --------------------- pass B (wave-per-point) + fused decide tail (+output)
__global__ __launch_bounds__(256, 4) void k_passB(const float* __restrict__ qgg,
        const float* __restrict__ feat0, const float* __restrict__ pts0,
        float* __restrict__ st, float* __restrict__ ncostp,
        int* __restrict__ cnt, int iter, float* __restrict__ out) {
    const int w = threadIdx.x >> 6, lane = threadIdx.x & 63;
    const int n = blockIdx.x * 4 + w;
    const float p0 = pts0[n*3+0], p1 = pts0[n*3+1], p2 = pts0[n*3+2];
    // npts = pts0 @ R_new.T + t_new (row-dot)
    const float X = p0*st[14] + p1*st[15] + p2*st[16] + st[23];
    const float Y = p0*st[17] + p1*st[18] + p2*st[19] + st[24];
    const float Z = p0*st[20] + p1*st[21] + p2*st[22] + st[25];
    const float hx = st[32]*X + st[33]*Y + st[34]*Z;
    const float hy = st[35]*X + st[36]*Y + st[37]*Z;
    const float hz = st[38]*X + st[39]*Y + st[40]*Z;
    const float sr = st[43];
    const float u = hx / hz, v = hy / hz;
    int ix = (int)floorf(u / sr); ix = min(max(ix, 0), W_-1);
    int iy = (int)floorf(v / sr); iy = min(max(iy, 0), H_-1);
    const int pix = iy * W_ + ix;

    const float4* row4 = (const float4*)(qgg + (size_t)pix * ROWF);
    const float4* f4   = (const float4*)(feat0 + (size_t)n * C_);
    float cost = 0;
#pragma unroll
    for (int i = 0; i < 4; i++) {
        float4 qv = row4[lane + 64*i], fv = f4[lane + 64*i];
        float e;
        e = qv.x - fv.x; cost += e*e;
        e = qv.y - fv.y; cost += e*e;
        e = qv.z - fv.z; cost += e*e;
        e = qv.w - fv.w; cost += e*e;
    }
#pragma unroll
    for (int off = 32; off; off >>= 1) cost += __shfl_xor(cost, off, 64);

    __shared__ float pl[4];
    __shared__ int lastFlag;
    if (lane == 0) pl[w] = cost;
    __syncthreads();
    if (threadIdx.x == 0)
        __hip_atomic_store(&ncostp[blockIdx.x], pl[0] + pl[1] + pl[2] + pl[3],
                           __ATOMIC_RELAXED, __HIP_MEMORY_SCOPE_AGENT);
    __syncthreads();  // drains vmcnt
    if (threadIdx.x == 0) {
        int old = __hip_atomic_fetch_add(&cnt[16 + iter], 1, __ATOMIC_RELAXED,
                                         __HIP_MEMORY_SCOPE_AGENT);
        lastFlag = (old == NB_ - 1);
    }
    __syncthreads();
    if (!lastFlag) return;

    // ---- tail: deterministic cost reduction (same order as previous k_decide)
    if (threadIdx.x >= 64) return;
    double s = 0;
#pragma unroll 4
    for (int i = 0; i < NB_/64; i++)
        s += (double)__hip_atomic_load(&ncostp[i*64 + lane],
                                       __ATOMIC_RELAXED, __HIP_MEMORY_SCOPE_AGENT);
    for (int off = 32; off; off >>= 1) s += __shfl_down(s, off, 64);
    if (lane == 0) {
        float nc = (float)(s / (double)N_);
        float prev = st[13], lam = st[12];
        bool bad = isnan(nc) || (st[72] != 0.f);
        bool worse = nc > prev;
        float lu = lam * (worse ? 10.f : 0.1f);
        lu = fminf(fmaxf(lu, 1e-6f), 100.f);
        st[12] = bad ? lam : lu;
        bool accept = !(worse || bad);
        if (accept) {
            for (int i = 0; i < 9; i++) st[i] = st[14+i];
            for (int i = 0; i < 3; i++) st[9+i] = st[23+i];
            st[13] = nc;
        }
        if (iter == ITERS - 1)
            for (int i = 0; i < 12; i++) out[i] = st[i];
    }
}

extern "C" void kernel_launch(void* const* d_in, const int* in_sizes, int n_in,
                              void* d_out, int out_size, void* d_ws, size_t ws_size,
                              hipStream_t stream) {
    const float* q   = (const float*)d_in[0];
    const float* r   = (const float*)d_in[1];
    const float* p2d = (const float*)d_in[2];
    const float* p3d = (const float*)d_in[3];
    const float* qf  = (const float*)d_in[4];
    const float* rf  = (const float*)d_in[5];
    const float* K1  = (const float*)d_in[6];
    const int*   srp = (const int*)d_in[7];

    float* ws = (float*)d_ws;
    size_t off = 0;
    float* qgg   = ws + off; off += (size_t)HW_ * ROWF;   // 192 MB interleaved q|gx|gy
    float* feat0 = ws + off; off += (size_t)N_ * C_;      // 32 MB
    float* pts0  = ws + off; off += 3 * N_;
    int*   pix0  = (int*)(ws + off); off += N_;
    float* partial = ws + off; off += (size_t)NCOMP * NB_;
    float* ncostp  = ws + off; off += NB_;
    float* st    = ws + off; off += 128;
    int*   cnt   = (int*)(ws + off); off += 32;

    k_setup<<<N_/256, 256, 0, stream>>>(q, r, K1, srp, p3d, p2d, st, pts0, pix0, cnt);
    k_feat0d<<<NB_, 256, 0, stream>>>(rf, pix0, feat0);
    k_sobelT<<<dim3(W_/32, H_/4, C_/32), 256, 0, stream>>>(qf, qgg);

    for (int it = 0; it < ITERS; it++) {
        k_passA<<<NB_, 256, 0, stream>>>(qgg, feat0, pts0, st, partial, cnt, it);
        k_passB<<<NB_, 256, 0, stream>>>(qgg, feat0, pts0, st, ncostp, cnt, it, (float*)d_out);
    }
}